// Round 6
// baseline (556.892 us; speedup 1.0000x reference)
//
#include <hip/hip_runtime.h>

#define EPS 1e-5f
#define BSHIFT 8
#define BSIZE  256
#define NBMAX  512   // covers N up to 131072 with 256-node buckets

__device__ __forceinline__ unsigned short f2bf(float f) {
    unsigned u = __float_as_uint(f);
    u += 0x7FFFu + ((u >> 16) & 1u);     // round-to-nearest-even
    return (unsigned short)(u >> 16);
}
__device__ __forceinline__ float bf2f(unsigned short s) {
    return __uint_as_float(((unsigned)s) << 16);
}

__global__ __launch_bounds__(512) void k_zero(unsigned* ghist, float* scal, int NB) {
    int t = threadIdx.x;
    if (t < NB) ghist[t] = 0u;
    if (t == 0) { scal[0] = 0.f; scal[1] = 0.f; }
}

// bucket histogram: LDS-aggregated (4096 edges/block)
__global__ __launch_bounds__(256) void k_bhist(const int* __restrict__ ei,
                                               unsigned* __restrict__ ghist, int E, int NB) {
    __shared__ unsigned sh[NBMAX];
    int t = threadIdx.x;
    for (int i = t; i < NB; i += 256) sh[i] = 0u;
    __syncthreads();
    const int4* dst4 = (const int4*)(ei + E);
    int E4 = E >> 2;
    int base4 = blockIdx.x * 1024;
#pragma unroll
    for (int i = 0; i < 4; i++) {
        int idx = base4 + i * 256 + t;
        if (idx < E4) {
            int4 d = dst4[idx];
            atomicAdd(&sh[d.x >> BSHIFT], 1u);
            atomicAdd(&sh[d.y >> BSHIFT], 1u);
            atomicAdd(&sh[d.z >> BSHIFT], 1u);
            atomicAdd(&sh[d.w >> BSHIFT], 1u);
        }
    }
    __syncthreads();
    for (int i = t; i < NB; i += 256) if (sh[i]) atomicAdd(&ghist[i], sh[i]);
}

// exclusive scan of ghist[NB] (NB <= 512) -> base, cursor; sentinels
__global__ __launch_bounds__(512) void k_bscan(const unsigned* __restrict__ ghist,
                                               unsigned* __restrict__ base,
                                               unsigned* __restrict__ cursor,
                                               unsigned* __restrict__ nstart,
                                               int NB, int N, int E) {
    __shared__ unsigned sh[512];
    int t = threadIdx.x;
    unsigned v = (t < NB) ? ghist[t] : 0u;
    sh[t] = v;
    __syncthreads();
    for (int off = 1; off < 512; off <<= 1) {
        unsigned a = (t >= off) ? sh[t - off] : 0u;
        __syncthreads();
        sh[t] += a;
        __syncthreads();
    }
    if (t < NB) { unsigned ex = sh[t] - v; base[t] = ex; cursor[t] = ex; }
    if (t == 0) { base[NB] = (unsigned)E; nstart[N] = (unsigned)E; }
}

// partition edges into bucket streams; packed u32 = src | (dst&255)<<17
__global__ __launch_bounds__(256) void k_bpart(const int* __restrict__ ei,
                                               unsigned* __restrict__ cursor,
                                               unsigned* __restrict__ sorted, int E, int NB) {
    __shared__ unsigned cnt[NBMAX];
    __shared__ unsigned lbase[NBMAX];
    int t = threadIdx.x;
    for (int i = t; i < NB; i += 256) cnt[i] = 0u;
    __syncthreads();
    const int4* src4 = (const int4*)ei;
    const int4* dst4 = (const int4*)(ei + E);
    int E4 = E >> 2;
    int base4 = blockIdx.x * 1024;
#pragma unroll
    for (int i = 0; i < 4; i++) {
        int idx = base4 + i * 256 + t;
        if (idx < E4) {
            int4 d = dst4[idx];
            atomicAdd(&cnt[d.x >> BSHIFT], 1u);
            atomicAdd(&cnt[d.y >> BSHIFT], 1u);
            atomicAdd(&cnt[d.z >> BSHIFT], 1u);
            atomicAdd(&cnt[d.w >> BSHIFT], 1u);
        }
    }
    __syncthreads();
    for (int i = t; i < NB; i += 256) {
        unsigned c = cnt[i];
        lbase[i] = c ? atomicAdd(&cursor[i], c) : 0u;
        cnt[i] = 0u;
    }
    __syncthreads();
#pragma unroll
    for (int i = 0; i < 4; i++) {
        int idx = base4 + i * 256 + t;
        if (idx < E4) {
            int4 s = src4[idx];
            int4 d = dst4[idx];
            {
                int b = d.x >> BSHIFT; unsigned off = atomicAdd(&cnt[b], 1u);
                sorted[lbase[b] + off] = (unsigned)s.x | ((unsigned)(d.x & (BSIZE - 1)) << 17);
            }
            {
                int b = d.y >> BSHIFT; unsigned off = atomicAdd(&cnt[b], 1u);
                sorted[lbase[b] + off] = (unsigned)s.y | ((unsigned)(d.y & (BSIZE - 1)) << 17);
            }
            {
                int b = d.z >> BSHIFT; unsigned off = atomicAdd(&cnt[b], 1u);
                sorted[lbase[b] + off] = (unsigned)s.z | ((unsigned)(d.z & (BSIZE - 1)) << 17);
            }
            {
                int b = d.w >> BSHIFT; unsigned off = atomicAdd(&cnt[b], 1u);
                sorted[lbase[b] + off] = (unsigned)s.w | ((unsigned)(d.w & (BSIZE - 1)) << 17);
            }
        }
    }
}

// per-bucket degree count + block scan -> nstart (global CSR row starts) + dinv
__global__ __launch_bounds__(256) void k_bdeg2(const unsigned* __restrict__ base,
                                               const unsigned* __restrict__ sorted,
                                               unsigned* __restrict__ nstart,
                                               float* __restrict__ dinv, int N) {
    __shared__ unsigned deg[BSIZE];
    int b = blockIdx.x, t = threadIdx.x;
    deg[t] = 0u;
    __syncthreads();
    unsigned s0 = base[b], s1 = base[b + 1];
    for (unsigned j = s0 + t; j < s1; j += 256)
        atomicAdd(&deg[sorted[j] >> 17], 1u);
    __syncthreads();
    unsigned d0 = deg[t];
    int lane = t & 63, wid = t >> 6;
    unsigned inc = d0;
    for (int off = 1; off < 64; off <<= 1) {
        unsigned u = __shfl_up(inc, off, 64);
        if (lane >= off) inc += u;
    }
    __shared__ unsigned wsum[4];
    if (lane == 63) wsum[wid] = inc;
    __syncthreads();
    unsigned wbase = 0;
    for (int w = 0; w < wid; w++) wbase += wsum[w];
    unsigned excl = wbase + inc - d0;
    int node = (b << BSHIFT) + t;
    if (node < N) {
        nstart[node] = s0 + excl;
        dinv[node] = rsqrtf((float)(d0 + 1u));   // +1 = self-loop
    }
}

// hs[n][r] = (sum_k x[n][k]*W[r][k]) * dinv[n], stored bf16.
__global__ __launch_bounds__(256) void k_gemm(const float* __restrict__ x,
                                              const float* __restrict__ W,
                                              const float* __restrict__ dinv,
                                              unsigned short* __restrict__ hs, int N) {
    __shared__ float ws[16 * 256];       // W fp32, 16KB
    int t = threadIdx.x;
    for (int i = t; i < 1024; i += 256) ((float4*)ws)[i] = ((const float4*)W)[i];
    __syncthreads();
    int node = blockIdx.x * 256 + t;
    if (node >= N) return;
    const float4* xr = (const float4*)(x + (size_t)node * 256);
    float acc[16];
#pragma unroll
    for (int r = 0; r < 16; r++) acc[r] = 0.f;
#pragma unroll 4
    for (int k = 0; k < 64; k++) {
        float4 a = xr[k];
#pragma unroll
        for (int r = 0; r < 16; r++) {
            float4 w = ((const float4*)ws)[r * 64 + k];   // wave-broadcast LDS read
            acc[r] += a.x * w.x + a.y * w.y + a.z * w.z + a.w * w.w;
        }
    }
    float dv = dinv[node];
    unsigned pk[8];
#pragma unroll
    for (int i = 0; i < 8; i++)
        pk[i] = (unsigned)f2bf(acc[2 * i] * dv) | ((unsigned)f2bf(acc[2 * i + 1] * dv) << 16);
    uint4* dst = (uint4*)(hs + (size_t)node * 16);
    dst[0] = make_uint4(pk[0], pk[1], pk[2], pk[3]);
    dst[1] = make_uint4(pk[4], pk[5], pk[6], pk[7]);
}

// counting-sort placement that MATERIALIZES the 32B hs row at its CSR slot.
// Gather feeds only stores -> latency fully pipelineable.
__global__ __launch_bounds__(256) void k_bsortrow(const unsigned* __restrict__ base,
                                                  const unsigned* __restrict__ nstart,
                                                  const unsigned* __restrict__ sorted,
                                                  const unsigned short* __restrict__ hs,
                                                  unsigned short* __restrict__ rows, int N) {
    __shared__ unsigned cur[BSIZE];
    int b = blockIdx.x, t = threadIdx.x;
    int node = (b << BSHIFT) + t;
    cur[t] = (node < N) ? nstart[node] : 0u;
    __syncthreads();
    unsigned s0 = base[b], s1 = base[b + 1];
    for (unsigned j = s0 + t; j < s1; j += 256) {
        unsigned u = sorted[j];
        unsigned src = u & 0x1FFFFu;
        unsigned pos = atomicAdd(&cur[u >> 17], 1u);
        const uint4* hp = (const uint4*)(hs + (size_t)src * 16);
        uint4 a = hp[0], c = hp[1];
        uint4* rp = (uint4*)(rows + (size_t)pos * 16);
        rp[0] = a; rp[1] = c;
    }
}

// streaming pull aggregation: 16 lanes per node read contiguous 32B rows.
// agg[d][r] = (sum_seg rows[j][r] + hs[d][r]) * dinv[d]; fused LN stats.
__global__ __launch_bounds__(256) void k_agg2(const unsigned* __restrict__ nstart,
                                              const unsigned short* __restrict__ rows,
                                              const unsigned short* __restrict__ hs,
                                              const float* __restrict__ dinv,
                                              const float* __restrict__ bias,
                                              float* __restrict__ agg,
                                              float* __restrict__ scal, int N) {
    int t = threadIdx.x;
    int g = t >> 4, r = t & 15;
    int d = blockIdx.x * 16 + g;
    float sv = 0.f;
    if (d < N) {
        unsigned s0 = nstart[d], s1 = nstart[d + 1];
        float acc = 0.f;
        unsigned j = s0;
        for (; j + 4 <= s1; j += 4) {
            float v0 = bf2f(rows[(size_t)(j + 0) * 16 + r]);
            float v1 = bf2f(rows[(size_t)(j + 1) * 16 + r]);
            float v2 = bf2f(rows[(size_t)(j + 2) * 16 + r]);
            float v3 = bf2f(rows[(size_t)(j + 3) * 16 + r]);
            acc += (v0 + v1) + (v2 + v3);
        }
        for (; j < s1; j++) acc += bf2f(rows[(size_t)j * 16 + r]);
        float o = (acc + bf2f(hs[(size_t)d * 16 + r])) * dinv[d];
        agg[(size_t)d * 16 + r] = o;
        sv = o + bias[r];
    }
    float s = sv, q = sv * sv;
    for (int off = 32; off > 0; off >>= 1) {
        s += __shfl_down(s, off, 64);
        q += __shfl_down(q, off, 64);
    }
    __shared__ float ss[4], qq[4];
    int lane = t & 63, wid = t >> 6;
    if (lane == 0) { ss[wid] = s; qq[wid] = q; }
    __syncthreads();
    if (t == 0) {
        atomicAdd(&scal[0], ss[0] + ss[1] + ss[2] + ss[3]);
        atomicAdd(&scal[1], qq[0] + qq[1] + qq[2] + qq[3]);
    }
}

// per batch row: LN + PReLU on 16 channels, then x trans[16,128] -> out[B,128]
__global__ __launch_bounds__(256) void k_final(const float* __restrict__ agg,
                                               const int* __restrict__ batch,
                                               const float* __restrict__ trans,
                                               const float* __restrict__ bias,
                                               const float* __restrict__ ln_w,
                                               const float* __restrict__ ln_b,
                                               const float* __restrict__ prelu_a,
                                               const float* __restrict__ scal,
                                               float* __restrict__ out, int B, float invCnt) {
    __shared__ float tl[16 * 128];
    __shared__ float hh[2 * 16];
    const int tid = threadIdx.x;
    for (int i = tid; i < 2048; i += 256) tl[i] = trans[i];
    float mean = scal[0] * invCnt;
    float var  = scal[1] * invCnt - mean * mean;
    float inv  = rsqrtf(var + EPS);
    int row0 = blockIdx.x * 2;
    if (tid < 32) {
        int lr = tid >> 4, r = tid & 15;
        int row = row0 + lr;
        if (row < B) {
            int node = batch[row];
            float v = agg[(size_t)node * 16 + r] + bias[r];
            v = (v - mean) * inv * ln_w[r] + ln_b[r];
            float a = prelu_a[0];
            v = v >= 0.f ? v : a * v;
            hh[lr * 16 + r] = v;
        }
    }
    __syncthreads();
    int lr = tid >> 7, d = tid & 127;
    int row = row0 + lr;
    if (row >= B) return;
    const float* hrow = hh + lr * 16;
    float acc = 0.f;
#pragma unroll
    for (int r = 0; r < 16; r++) acc += hrow[r] * tl[r * 128 + d];
    out[(size_t)row * 128 + d] = acc;
}

extern "C" void kernel_launch(void* const* d_in, const int* in_sizes, int n_in,
                              void* d_out, int out_size, void* d_ws, size_t ws_size,
                              hipStream_t stream) {
    const float* x       = (const float*)d_in[0];
    const int*   ei      = (const int*)d_in[1];
    const float* trans   = (const float*)d_in[2];
    const int*   batch   = (const int*)d_in[3];
    const float* W       = (const float*)d_in[4];
    const float* bias    = (const float*)d_in[5];
    const float* ln_w    = (const float*)d_in[6];
    const float* ln_b    = (const float*)d_in[7];
    const float* prelu_a = (const float*)d_in[8];
    float* out = (float*)d_out;

    const int N = in_sizes[0] / 256;   // 100000
    const int E = in_sizes[1] / 2;     // 3200000
    const int B = in_sizes[3];         // 16384
    const int NB = (N + BSIZE - 1) >> BSHIFT;   // 391

    char* p = (char*)d_ws;
    unsigned short* hs = (unsigned short*)p;  p += (size_t)N * 16 * 2;    // 3.2MB bf16
    float*    agg     = (float*)p;     p += (size_t)N * 16 * 4;           // 6.4MB
    unsigned* sorted  = (unsigned*)p;  p += (size_t)E * 4;                // 12.8MB
    float*    dinv    = (float*)p;     p += (size_t)N * 4;
    unsigned* nstart  = (unsigned*)p;  p += (size_t)(N + 1) * 4;
    unsigned* ghist   = (unsigned*)p;  p += NBMAX * 4;
    unsigned* base    = (unsigned*)p;  p += (NBMAX + 1) * 4;
    unsigned* cursor  = (unsigned*)p;  p += NBMAX * 4;
    float*    scal    = (float*)p;     p += 2 * 4;
    p = (char*)(((size_t)p + 255) & ~(size_t)255);
    unsigned short* rows = (unsigned short*)p; p += (size_t)E * 16 * 2;   // 102.4MB

    int E4 = E >> 2;
    int pb = (E4 + 1023) / 1024;       // 4096 edges per block

    hipLaunchKernelGGL(k_zero,     dim3(1),               dim3(512), 0, stream, ghist, scal, NB);
    hipLaunchKernelGGL(k_bhist,    dim3(pb),              dim3(256), 0, stream, ei, ghist, E, NB);
    hipLaunchKernelGGL(k_bscan,    dim3(1),               dim3(512), 0, stream, ghist, base, cursor, nstart, NB, N, E);
    hipLaunchKernelGGL(k_bpart,    dim3(pb),              dim3(256), 0, stream, ei, cursor, sorted, E, NB);
    hipLaunchKernelGGL(k_bdeg2,    dim3(NB),              dim3(256), 0, stream, base, sorted, nstart, dinv, N);
    hipLaunchKernelGGL(k_gemm,     dim3((N + 255) / 256), dim3(256), 0, stream, x, W, dinv, hs, N);
    hipLaunchKernelGGL(k_bsortrow, dim3(NB),              dim3(256), 0, stream, base, nstart, sorted, hs, rows, N);
    hipLaunchKernelGGL(k_agg2,     dim3((N + 15) / 16),   dim3(256), 0, stream, nstart, rows, hs, dinv, bias, agg, scal, N);
    hipLaunchKernelGGL(k_final,    dim3((B + 1) / 2),     dim3(256), 0, stream, agg, batch, trans, bias,
                       ln_w, ln_b, prelu_a, scal, out, B, 1.0f / (float)(N * 16));
}

// Round 7
// 496.550 us; speedup vs baseline: 1.1215x; 1.1215x over previous
//
#include <hip/hip_runtime.h>

#define EPS 1e-5f
#define BSHIFT 8
#define BSIZE  256
#define NBMAX  512   // covers N up to 131072 with 256-node buckets

__device__ __forceinline__ unsigned short f2bf(float f) {
    unsigned u = __float_as_uint(f);
    u += 0x7FFFu + ((u >> 16) & 1u);     // round-to-nearest-even
    return (unsigned short)(u >> 16);
}
__device__ __forceinline__ float bf2f(unsigned short s) {
    return __uint_as_float(((unsigned)s) << 16);
}
__device__ __forceinline__ void acc8(float* acc, uint4 v) {
    acc[0] += bf2f((unsigned short)(v.x & 0xFFFFu)); acc[1] += bf2f((unsigned short)(v.x >> 16));
    acc[2] += bf2f((unsigned short)(v.y & 0xFFFFu)); acc[3] += bf2f((unsigned short)(v.y >> 16));
    acc[4] += bf2f((unsigned short)(v.z & 0xFFFFu)); acc[5] += bf2f((unsigned short)(v.z >> 16));
    acc[6] += bf2f((unsigned short)(v.w & 0xFFFFu)); acc[7] += bf2f((unsigned short)(v.w >> 16));
}

__global__ __launch_bounds__(512) void k_zero(unsigned* ghist, float* scal, int NB) {
    int t = threadIdx.x;
    if (t < NB) ghist[t] = 0u;
    if (t == 0) { scal[0] = 0.f; scal[1] = 0.f; }
}

// bucket histogram: LDS-aggregated (4096 edges/block)
__global__ __launch_bounds__(256) void k_bhist(const int* __restrict__ ei,
                                               unsigned* __restrict__ ghist, int E, int NB) {
    __shared__ unsigned sh[NBMAX];
    int t = threadIdx.x;
    for (int i = t; i < NB; i += 256) sh[i] = 0u;
    __syncthreads();
    const int4* dst4 = (const int4*)(ei + E);
    int E4 = E >> 2;
    int base4 = blockIdx.x * 1024;
#pragma unroll
    for (int i = 0; i < 4; i++) {
        int idx = base4 + i * 256 + t;
        if (idx < E4) {
            int4 d = dst4[idx];
            atomicAdd(&sh[d.x >> BSHIFT], 1u);
            atomicAdd(&sh[d.y >> BSHIFT], 1u);
            atomicAdd(&sh[d.z >> BSHIFT], 1u);
            atomicAdd(&sh[d.w >> BSHIFT], 1u);
        }
    }
    __syncthreads();
    for (int i = t; i < NB; i += 256) if (sh[i]) atomicAdd(&ghist[i], sh[i]);
}

// exclusive scan of ghist[NB] (NB <= 512) -> base, cursor; sentinels
__global__ __launch_bounds__(512) void k_bscan(const unsigned* __restrict__ ghist,
                                               unsigned* __restrict__ base,
                                               unsigned* __restrict__ cursor,
                                               unsigned* __restrict__ nstart,
                                               int NB, int N, int E) {
    __shared__ unsigned sh[512];
    int t = threadIdx.x;
    unsigned v = (t < NB) ? ghist[t] : 0u;
    sh[t] = v;
    __syncthreads();
    for (int off = 1; off < 512; off <<= 1) {
        unsigned a = (t >= off) ? sh[t - off] : 0u;
        __syncthreads();
        sh[t] += a;
        __syncthreads();
    }
    if (t < NB) { unsigned ex = sh[t] - v; base[t] = ex; cursor[t] = ex; }
    if (t == 0) { base[NB] = (unsigned)E; nstart[N] = (unsigned)E; }
}

// partition edges into bucket streams; packed u32 = src | (dst&255)<<17
__global__ __launch_bounds__(256) void k_bpart(const int* __restrict__ ei,
                                               unsigned* __restrict__ cursor,
                                               unsigned* __restrict__ sorted, int E, int NB) {
    __shared__ unsigned cnt[NBMAX];
    __shared__ unsigned lbase[NBMAX];
    int t = threadIdx.x;
    for (int i = t; i < NB; i += 256) cnt[i] = 0u;
    __syncthreads();
    const int4* src4 = (const int4*)ei;
    const int4* dst4 = (const int4*)(ei + E);
    int E4 = E >> 2;
    int base4 = blockIdx.x * 1024;
#pragma unroll
    for (int i = 0; i < 4; i++) {
        int idx = base4 + i * 256 + t;
        if (idx < E4) {
            int4 d = dst4[idx];
            atomicAdd(&cnt[d.x >> BSHIFT], 1u);
            atomicAdd(&cnt[d.y >> BSHIFT], 1u);
            atomicAdd(&cnt[d.z >> BSHIFT], 1u);
            atomicAdd(&cnt[d.w >> BSHIFT], 1u);
        }
    }
    __syncthreads();
    for (int i = t; i < NB; i += 256) {
        unsigned c = cnt[i];
        lbase[i] = c ? atomicAdd(&cursor[i], c) : 0u;
        cnt[i] = 0u;
    }
    __syncthreads();
#pragma unroll
    for (int i = 0; i < 4; i++) {
        int idx = base4 + i * 256 + t;
        if (idx < E4) {
            int4 s = src4[idx];
            int4 d = dst4[idx];
            {
                int b = d.x >> BSHIFT; unsigned off = atomicAdd(&cnt[b], 1u);
                sorted[lbase[b] + off] = (unsigned)s.x | ((unsigned)(d.x & (BSIZE - 1)) << 17);
            }
            {
                int b = d.y >> BSHIFT; unsigned off = atomicAdd(&cnt[b], 1u);
                sorted[lbase[b] + off] = (unsigned)s.y | ((unsigned)(d.y & (BSIZE - 1)) << 17);
            }
            {
                int b = d.z >> BSHIFT; unsigned off = atomicAdd(&cnt[b], 1u);
                sorted[lbase[b] + off] = (unsigned)s.z | ((unsigned)(d.z & (BSIZE - 1)) << 17);
            }
            {
                int b = d.w >> BSHIFT; unsigned off = atomicAdd(&cnt[b], 1u);
                sorted[lbase[b] + off] = (unsigned)s.w | ((unsigned)(d.w & (BSIZE - 1)) << 17);
            }
        }
    }
}

// per-bucket degree count + block scan -> nstart (global CSR row starts) + dinv
__global__ __launch_bounds__(256) void k_bdeg2(const unsigned* __restrict__ base,
                                               const unsigned* __restrict__ sorted,
                                               unsigned* __restrict__ nstart,
                                               float* __restrict__ dinv, int N) {
    __shared__ unsigned deg[BSIZE];
    int b = blockIdx.x, t = threadIdx.x;
    deg[t] = 0u;
    __syncthreads();
    unsigned s0 = base[b], s1 = base[b + 1];
    for (unsigned j = s0 + t; j < s1; j += 256)
        atomicAdd(&deg[sorted[j] >> 17], 1u);
    __syncthreads();
    unsigned d0 = deg[t];
    int lane = t & 63, wid = t >> 6;
    unsigned inc = d0;
    for (int off = 1; off < 64; off <<= 1) {
        unsigned u = __shfl_up(inc, off, 64);
        if (lane >= off) inc += u;
    }
    __shared__ unsigned wsum[4];
    if (lane == 63) wsum[wid] = inc;
    __syncthreads();
    unsigned wbase = 0;
    for (int w = 0; w < wid; w++) wbase += wsum[w];
    unsigned excl = wbase + inc - d0;
    int node = (b << BSHIFT) + t;
    if (node < N) {
        nstart[node] = s0 + excl;
        dinv[node] = rsqrtf((float)(d0 + 1u));   // +1 = self-loop
    }
}

// per-bucket counting-sort placement -> sorted2[j] = src, dst-sorted CSR order
__global__ __launch_bounds__(256) void k_bsort(const unsigned* __restrict__ base,
                                               const unsigned* __restrict__ nstart,
                                               const unsigned* __restrict__ sorted,
                                               unsigned* __restrict__ sorted2, int N) {
    __shared__ unsigned cur[BSIZE];
    int b = blockIdx.x, t = threadIdx.x;
    int node = (b << BSHIFT) + t;
    cur[t] = (node < N) ? nstart[node] : 0u;
    __syncthreads();
    unsigned s0 = base[b], s1 = base[b + 1];
    for (unsigned j = s0 + t; j < s1; j += 256) {
        unsigned u = sorted[j];
        unsigned pos = atomicAdd(&cur[u >> 17], 1u);
        sorted2[pos] = u & 0x1FFFFu;
    }
}

// hs[n][r] = (sum_k x[n][k]*W[r][k]) * dinv[n], stored bf16.
__global__ __launch_bounds__(256) void k_gemm(const float* __restrict__ x,
                                              const float* __restrict__ W,
                                              const float* __restrict__ dinv,
                                              unsigned short* __restrict__ hs, int N) {
    __shared__ float ws[16 * 256];       // W fp32, 16KB
    int t = threadIdx.x;
    for (int i = t; i < 1024; i += 256) ((float4*)ws)[i] = ((const float4*)W)[i];
    __syncthreads();
    int node = blockIdx.x * 256 + t;
    if (node >= N) return;
    const float4* xr = (const float4*)(x + (size_t)node * 256);
    float acc[16];
#pragma unroll
    for (int r = 0; r < 16; r++) acc[r] = 0.f;
#pragma unroll 4
    for (int k = 0; k < 64; k++) {
        float4 a = xr[k];
#pragma unroll
        for (int r = 0; r < 16; r++) {
            float4 w = ((const float4*)ws)[r * 64 + k];   // wave-broadcast LDS read
            acc[r] += a.x * w.x + a.y * w.y + a.z * w.z + a.w * w.w;
        }
    }
    float dv = dinv[node];
    unsigned pk[8];
#pragma unroll
    for (int i = 0; i < 8; i++)
        pk[i] = (unsigned)f2bf(acc[2 * i] * dv) | ((unsigned)f2bf(acc[2 * i + 1] * dv) << 16);
    uint4* dst = (uint4*)(hs + (size_t)node * 16);
    dst[0] = make_uint4(pk[0], pk[1], pk[2], pk[3]);
    dst[1] = make_uint4(pk[4], pk[5], pk[6], pk[7]);
}

// wide-load pull aggregation: 16 lanes per node; lane r handles rows j+(r>>1)
// and channel-half (r&1), loading full uint4 (8 bf16) per row.
// 8 edges consumed per lane-load-instruction (vs 1/16 before).
__global__ __launch_bounds__(256) void k_agg3(const unsigned* __restrict__ nstart,
                                              const unsigned* __restrict__ sorted2,
                                              const unsigned short* __restrict__ hs,
                                              const float* __restrict__ dinv,
                                              const float* __restrict__ bias,
                                              float* __restrict__ agg,
                                              float* __restrict__ scal, int N) {
    int t = threadIdx.x;
    int g = t >> 4, r = t & 15;
    int d = blockIdx.x * 16 + g;
    int sub = r >> 1;                    // row offset 0..7
    int half = r & 1;                    // channel half
    float acc[8];
#pragma unroll
    for (int c = 0; c < 8; c++) acc[c] = 0.f;
    unsigned s0 = 0, s1 = 0;
    if (d < N) { s0 = nstart[d]; s1 = nstart[d + 1]; }
    for (unsigned j = s0; j < s1; j += 16) {
        unsigned row0 = j + sub, row1 = j + 8 + sub;
        bool p0 = row0 < s1, p1 = row1 < s1;
        unsigned i0 = 0, i1 = 0;
        if (p0) i0 = sorted2[row0];
        if (p1) i1 = sorted2[row1];
        uint4 v0, v1;
        if (p0) v0 = ((const uint4*)(hs + (size_t)i0 * 16))[half];
        if (p1) v1 = ((const uint4*)(hs + (size_t)i1 * 16))[half];
        if (p0) acc8(acc, v0);
        if (p1) acc8(acc, v1);
    }
    // reduce across stride-2 lanes (rows residues); lanes 0/1 of each group get totals.
#pragma unroll
    for (int off = 2; off <= 8; off <<= 1) {
#pragma unroll
        for (int c = 0; c < 8; c++) acc[c] += __shfl_down(acc[c], off, 64);
    }
    float s = 0.f, q = 0.f;
    if (d < N && r < 2) {
        float dd = dinv[d];
        uint4 hv = ((const uint4*)(hs + (size_t)d * 16))[half];
        float self[8];
        self[0] = bf2f((unsigned short)(hv.x & 0xFFFFu)); self[1] = bf2f((unsigned short)(hv.x >> 16));
        self[2] = bf2f((unsigned short)(hv.y & 0xFFFFu)); self[3] = bf2f((unsigned short)(hv.y >> 16));
        self[4] = bf2f((unsigned short)(hv.z & 0xFFFFu)); self[5] = bf2f((unsigned short)(hv.z >> 16));
        self[6] = bf2f((unsigned short)(hv.w & 0xFFFFu)); self[7] = bf2f((unsigned short)(hv.w >> 16));
        float o[8];
#pragma unroll
        for (int c = 0; c < 8; c++) o[c] = (acc[c] + self[c]) * dd;
        float* an = agg + (size_t)d * 16 + half * 8;
        *(float4*)(an)     = make_float4(o[0], o[1], o[2], o[3]);
        *(float4*)(an + 4) = make_float4(o[4], o[5], o[6], o[7]);
        const float* bp = bias + half * 8;
        float4 b0 = *(const float4*)bp, b1 = *(const float4*)(bp + 4);
        float a0 = o[0] + b0.x, a1 = o[1] + b0.y, a2 = o[2] + b0.z, a3 = o[3] + b0.w;
        float a4 = o[4] + b1.x, a5 = o[5] + b1.y, a6 = o[6] + b1.z, a7 = o[7] + b1.w;
        s = (a0 + a1) + (a2 + a3) + (a4 + a5) + (a6 + a7);
        q = a0 * a0 + a1 * a1 + a2 * a2 + a3 * a3 + a4 * a4 + a5 * a5 + a6 * a6 + a7 * a7;
    }
    for (int off = 32; off > 0; off >>= 1) {
        s += __shfl_down(s, off, 64);
        q += __shfl_down(q, off, 64);
    }
    __shared__ float ss[4], qq[4];
    int lane = t & 63, wid = t >> 6;
    if (lane == 0) { ss[wid] = s; qq[wid] = q; }
    __syncthreads();
    if (t == 0) {
        atomicAdd(&scal[0], ss[0] + ss[1] + ss[2] + ss[3]);
        atomicAdd(&scal[1], qq[0] + qq[1] + qq[2] + qq[3]);
    }
}

// per batch row: LN + PReLU on 16 channels, then x trans[16,128] -> out[B,128]
__global__ __launch_bounds__(256) void k_final(const float* __restrict__ agg,
                                               const int* __restrict__ batch,
                                               const float* __restrict__ trans,
                                               const float* __restrict__ bias,
                                               const float* __restrict__ ln_w,
                                               const float* __restrict__ ln_b,
                                               const float* __restrict__ prelu_a,
                                               const float* __restrict__ scal,
                                               float* __restrict__ out, int B, float invCnt) {
    __shared__ float tl[16 * 128];
    __shared__ float hh[2 * 16];
    const int tid = threadIdx.x;
    for (int i = tid; i < 2048; i += 256) tl[i] = trans[i];
    float mean = scal[0] * invCnt;
    float var  = scal[1] * invCnt - mean * mean;
    float inv  = rsqrtf(var + EPS);
    int row0 = blockIdx.x * 2;
    if (tid < 32) {
        int lr = tid >> 4, r = tid & 15;
        int row = row0 + lr;
        if (row < B) {
            int node = batch[row];
            float v = agg[(size_t)node * 16 + r] + bias[r];
            v = (v - mean) * inv * ln_w[r] + ln_b[r];
            float a = prelu_a[0];
            v = v >= 0.f ? v : a * v;
            hh[lr * 16 + r] = v;
        }
    }
    __syncthreads();
    int lr = tid >> 7, d = tid & 127;
    int row = row0 + lr;
    if (row >= B) return;
    const float* hrow = hh + lr * 16;
    float acc = 0.f;
#pragma unroll
    for (int r = 0; r < 16; r++) acc += hrow[r] * tl[r * 128 + d];
    out[(size_t)row * 128 + d] = acc;
}

extern "C" void kernel_launch(void* const* d_in, const int* in_sizes, int n_in,
                              void* d_out, int out_size, void* d_ws, size_t ws_size,
                              hipStream_t stream) {
    const float* x       = (const float*)d_in[0];
    const int*   ei      = (const int*)d_in[1];
    const float* trans   = (const float*)d_in[2];
    const int*   batch   = (const int*)d_in[3];
    const float* W       = (const float*)d_in[4];
    const float* bias    = (const float*)d_in[5];
    const float* ln_w    = (const float*)d_in[6];
    const float* ln_b    = (const float*)d_in[7];
    const float* prelu_a = (const float*)d_in[8];
    float* out = (float*)d_out;

    const int N = in_sizes[0] / 256;   // 100000
    const int E = in_sizes[1] / 2;     // 3200000
    const int B = in_sizes[3];         // 16384
    const int NB = (N + BSIZE - 1) >> BSHIFT;   // 391

    char* p = (char*)d_ws;
    unsigned short* hs = (unsigned short*)p;  p += (size_t)N * 16 * 2;    // 3.2MB bf16
    float*    agg     = (float*)p;     p += (size_t)N * 16 * 4;           // 6.4MB
    unsigned* sorted  = (unsigned*)p;  p += (size_t)E * 4;                // 12.8MB
    unsigned* sorted2 = (unsigned*)p;  p += (size_t)E * 4;                // 12.8MB
    float*    dinv    = (float*)p;     p += (size_t)N * 4;
    unsigned* nstart  = (unsigned*)p;  p += (size_t)(N + 1) * 4;
    unsigned* ghist   = (unsigned*)p;  p += NBMAX * 4;
    unsigned* base    = (unsigned*)p;  p += (NBMAX + 1) * 4;
    unsigned* cursor  = (unsigned*)p;  p += NBMAX * 4;
    float*    scal    = (float*)p;     p += 2 * 4;

    int E4 = E >> 2;
    int pb = (E4 + 1023) / 1024;       // 4096 edges per block

    hipLaunchKernelGGL(k_zero,  dim3(1),               dim3(512), 0, stream, ghist, scal, NB);
    hipLaunchKernelGGL(k_bhist, dim3(pb),              dim3(256), 0, stream, ei, ghist, E, NB);
    hipLaunchKernelGGL(k_bscan, dim3(1),               dim3(512), 0, stream, ghist, base, cursor, nstart, NB, N, E);
    hipLaunchKernelGGL(k_bpart, dim3(pb),              dim3(256), 0, stream, ei, cursor, sorted, E, NB);
    hipLaunchKernelGGL(k_bdeg2, dim3(NB),              dim3(256), 0, stream, base, sorted, nstart, dinv, N);
    hipLaunchKernelGGL(k_bsort, dim3(NB),              dim3(256), 0, stream, base, nstart, sorted, sorted2, N);
    hipLaunchKernelGGL(k_gemm,  dim3((N + 255) / 256), dim3(256), 0, stream, x, W, dinv, hs, N);
    hipLaunchKernelGGL(k_agg3,  dim3((N + 15) / 16),   dim3(256), 0, stream, nstart, sorted2, hs, dinv, bias, agg, scal, N);
    hipLaunchKernelGGL(k_final, dim3((B + 1) / 2),     dim3(256), 0, stream, agg, batch, trans, bias,
                       ln_w, ln_b, prelu_a, scal, out, B, 1.0f / (float)(N * 16));
}

// Round 8
// 364.333 us; speedup vs baseline: 1.5285x; 1.3629x over previous
//
#include <hip/hip_runtime.h>

#define EPS 1e-5f
#define BSHIFT 8
#define BSIZE  256
#define NBMAX  512   // covers N up to 131072 with 256-node buckets

__device__ __forceinline__ unsigned short f2bf(float f) {
    unsigned u = __float_as_uint(f);
    u += 0x7FFFu + ((u >> 16) & 1u);     // round-to-nearest-even
    return (unsigned short)(u >> 16);
}
__device__ __forceinline__ float bf2f(unsigned short s) {
    return __uint_as_float(((unsigned)s) << 16);
}
__device__ __forceinline__ void acc8(float* acc, uint4 v) {
    acc[0] += bf2f((unsigned short)(v.x & 0xFFFFu)); acc[1] += bf2f((unsigned short)(v.x >> 16));
    acc[2] += bf2f((unsigned short)(v.y & 0xFFFFu)); acc[3] += bf2f((unsigned short)(v.y >> 16));
    acc[4] += bf2f((unsigned short)(v.z & 0xFFFFu)); acc[5] += bf2f((unsigned short)(v.z >> 16));
    acc[6] += bf2f((unsigned short)(v.w & 0xFFFFu)); acc[7] += bf2f((unsigned short)(v.w >> 16));
}

__global__ __launch_bounds__(512) void k_zero(unsigned* ghist, int NB) {
    int t = threadIdx.x;
    if (t < NB) ghist[t] = 0u;
}

// bucket histogram: LDS-aggregated (4096 edges/block)
__global__ __launch_bounds__(256) void k_bhist(const int* __restrict__ ei,
                                               unsigned* __restrict__ ghist, int E, int NB) {
    __shared__ unsigned sh[NBMAX];
    int t = threadIdx.x;
    for (int i = t; i < NB; i += 256) sh[i] = 0u;
    __syncthreads();
    const int4* dst4 = (const int4*)(ei + E);
    int E4 = E >> 2;
    int base4 = blockIdx.x * 1024;
#pragma unroll
    for (int i = 0; i < 4; i++) {
        int idx = base4 + i * 256 + t;
        if (idx < E4) {
            int4 d = dst4[idx];
            atomicAdd(&sh[d.x >> BSHIFT], 1u);
            atomicAdd(&sh[d.y >> BSHIFT], 1u);
            atomicAdd(&sh[d.z >> BSHIFT], 1u);
            atomicAdd(&sh[d.w >> BSHIFT], 1u);
        }
    }
    __syncthreads();
    for (int i = t; i < NB; i += 256) if (sh[i]) atomicAdd(&ghist[i], sh[i]);
}

// exclusive scan of ghist[NB] (NB <= 512) -> base, cursor; sentinels
__global__ __launch_bounds__(512) void k_bscan(const unsigned* __restrict__ ghist,
                                               unsigned* __restrict__ base,
                                               unsigned* __restrict__ cursor,
                                               unsigned* __restrict__ nstart,
                                               int NB, int N, int E) {
    __shared__ unsigned sh[512];
    int t = threadIdx.x;
    unsigned v = (t < NB) ? ghist[t] : 0u;
    sh[t] = v;
    __syncthreads();
    for (int off = 1; off < 512; off <<= 1) {
        unsigned a = (t >= off) ? sh[t - off] : 0u;
        __syncthreads();
        sh[t] += a;
        __syncthreads();
    }
    if (t < NB) { unsigned ex = sh[t] - v; base[t] = ex; cursor[t] = ex; }
    if (t == 0) { base[NB] = (unsigned)E; nstart[N] = (unsigned)E; }
}

// partition edges into bucket streams; packed u32 = src | (dst&255)<<17
__global__ __launch_bounds__(256) void k_bpart(const int* __restrict__ ei,
                                               unsigned* __restrict__ cursor,
                                               unsigned* __restrict__ sorted, int E, int NB) {
    __shared__ unsigned cnt[NBMAX];
    __shared__ unsigned lbase[NBMAX];
    int t = threadIdx.x;
    for (int i = t; i < NB; i += 256) cnt[i] = 0u;
    __syncthreads();
    const int4* src4 = (const int4*)ei;
    const int4* dst4 = (const int4*)(ei + E);
    int E4 = E >> 2;
    int base4 = blockIdx.x * 1024;
#pragma unroll
    for (int i = 0; i < 4; i++) {
        int idx = base4 + i * 256 + t;
        if (idx < E4) {
            int4 d = dst4[idx];
            atomicAdd(&cnt[d.x >> BSHIFT], 1u);
            atomicAdd(&cnt[d.y >> BSHIFT], 1u);
            atomicAdd(&cnt[d.z >> BSHIFT], 1u);
            atomicAdd(&cnt[d.w >> BSHIFT], 1u);
        }
    }
    __syncthreads();
    for (int i = t; i < NB; i += 256) {
        unsigned c = cnt[i];
        lbase[i] = c ? atomicAdd(&cursor[i], c) : 0u;
        cnt[i] = 0u;
    }
    __syncthreads();
#pragma unroll
    for (int i = 0; i < 4; i++) {
        int idx = base4 + i * 256 + t;
        if (idx < E4) {
            int4 s = src4[idx];
            int4 d = dst4[idx];
            {
                int b = d.x >> BSHIFT; unsigned off = atomicAdd(&cnt[b], 1u);
                sorted[lbase[b] + off] = (unsigned)s.x | ((unsigned)(d.x & (BSIZE - 1)) << 17);
            }
            {
                int b = d.y >> BSHIFT; unsigned off = atomicAdd(&cnt[b], 1u);
                sorted[lbase[b] + off] = (unsigned)s.y | ((unsigned)(d.y & (BSIZE - 1)) << 17);
            }
            {
                int b = d.z >> BSHIFT; unsigned off = atomicAdd(&cnt[b], 1u);
                sorted[lbase[b] + off] = (unsigned)s.z | ((unsigned)(d.z & (BSIZE - 1)) << 17);
            }
            {
                int b = d.w >> BSHIFT; unsigned off = atomicAdd(&cnt[b], 1u);
                sorted[lbase[b] + off] = (unsigned)s.w | ((unsigned)(d.w & (BSIZE - 1)) << 17);
            }
        }
    }
}

// per-bucket degree count + block scan -> nstart (global CSR row starts) + dinv
__global__ __launch_bounds__(256) void k_bdeg2(const unsigned* __restrict__ base,
                                               const unsigned* __restrict__ sorted,
                                               unsigned* __restrict__ nstart,
                                               float* __restrict__ dinv, int N) {
    __shared__ unsigned deg[BSIZE];
    int b = blockIdx.x, t = threadIdx.x;
    deg[t] = 0u;
    __syncthreads();
    unsigned s0 = base[b], s1 = base[b + 1];
    for (unsigned j = s0 + t; j < s1; j += 256)
        atomicAdd(&deg[sorted[j] >> 17], 1u);
    __syncthreads();
    unsigned d0 = deg[t];
    int lane = t & 63, wid = t >> 6;
    unsigned inc = d0;
    for (int off = 1; off < 64; off <<= 1) {
        unsigned u = __shfl_up(inc, off, 64);
        if (lane >= off) inc += u;
    }
    __shared__ unsigned wsum[4];
    if (lane == 63) wsum[wid] = inc;
    __syncthreads();
    unsigned wbase = 0;
    for (int w = 0; w < wid; w++) wbase += wsum[w];
    unsigned excl = wbase + inc - d0;
    int node = (b << BSHIFT) + t;
    if (node < N) {
        nstart[node] = s0 + excl;
        dinv[node] = rsqrtf((float)(d0 + 1u));   // +1 = self-loop
    }
}

// per-bucket counting-sort placement -> sorted2[j] = src, dst-sorted CSR order
__global__ __launch_bounds__(256) void k_bsort(const unsigned* __restrict__ base,
                                               const unsigned* __restrict__ nstart,
                                               const unsigned* __restrict__ sorted,
                                               unsigned* __restrict__ sorted2, int N) {
    __shared__ unsigned cur[BSIZE];
    int b = blockIdx.x, t = threadIdx.x;
    int node = (b << BSHIFT) + t;
    cur[t] = (node < N) ? nstart[node] : 0u;
    __syncthreads();
    unsigned s0 = base[b], s1 = base[b + 1];
    for (unsigned j = s0 + t; j < s1; j += 256) {
        unsigned u = sorted[j];
        unsigned pos = atomicAdd(&cur[u >> 17], 1u);
        sorted2[pos] = u & 0x1FFFFu;
    }
}

// hs[n][r] = (sum_k x[n][k]*W[r][k]) * dinv[n], stored bf16.
__global__ __launch_bounds__(256) void k_gemm(const float* __restrict__ x,
                                              const float* __restrict__ W,
                                              const float* __restrict__ dinv,
                                              unsigned short* __restrict__ hs, int N) {
    __shared__ float ws[16 * 256];       // W fp32, 16KB
    int t = threadIdx.x;
    for (int i = t; i < 1024; i += 256) ((float4*)ws)[i] = ((const float4*)W)[i];
    __syncthreads();
    int node = blockIdx.x * 256 + t;
    if (node >= N) return;
    const float4* xr = (const float4*)(x + (size_t)node * 256);
    float acc[16];
#pragma unroll
    for (int r = 0; r < 16; r++) acc[r] = 0.f;
#pragma unroll 4
    for (int k = 0; k < 64; k++) {
        float4 a = xr[k];
#pragma unroll
        for (int r = 0; r < 16; r++) {
            float4 w = ((const float4*)ws)[r * 64 + k];   // wave-broadcast LDS read
            acc[r] += a.x * w.x + a.y * w.y + a.z * w.z + a.w * w.w;
        }
    }
    float dv = dinv[node];
    unsigned pk[8];
#pragma unroll
    for (int i = 0; i < 8; i++)
        pk[i] = (unsigned)f2bf(acc[2 * i] * dv) | ((unsigned)f2bf(acc[2 * i + 1] * dv) << 16);
    uint4* dst = (uint4*)(hs + (size_t)node * 16);
    dst[0] = make_uint4(pk[0], pk[1], pk[2], pk[3]);
    dst[1] = make_uint4(pk[4], pk[5], pk[6], pk[7]);
}

// wide-load pull aggregation: 16 lanes per node; lane r handles rows j+(r>>1)
// and channel-half (r&1), loading full uint4 (8 bf16) per row.
// LN-stats partial -> PLAIN float2 store per block (no same-address atomics).
__global__ __launch_bounds__(256) void k_agg3(const unsigned* __restrict__ nstart,
                                              const unsigned* __restrict__ sorted2,
                                              const unsigned short* __restrict__ hs,
                                              const float* __restrict__ dinv,
                                              const float* __restrict__ bias,
                                              float* __restrict__ agg,
                                              float2* __restrict__ part, int N) {
    int t = threadIdx.x;
    int g = t >> 4, r = t & 15;
    int d = blockIdx.x * 16 + g;
    int sub = r >> 1;                    // row offset 0..7
    int half = r & 1;                    // channel half
    float acc[8];
#pragma unroll
    for (int c = 0; c < 8; c++) acc[c] = 0.f;
    unsigned s0 = 0, s1 = 0;
    if (d < N) { s0 = nstart[d]; s1 = nstart[d + 1]; }
    for (unsigned j = s0; j < s1; j += 16) {
        unsigned row0 = j + sub, row1 = j + 8 + sub;
        bool p0 = row0 < s1, p1 = row1 < s1;
        unsigned i0 = 0, i1 = 0;
        if (p0) i0 = sorted2[row0];
        if (p1) i1 = sorted2[row1];
        uint4 v0, v1;
        if (p0) v0 = ((const uint4*)(hs + (size_t)i0 * 16))[half];
        if (p1) v1 = ((const uint4*)(hs + (size_t)i1 * 16))[half];
        if (p0) acc8(acc, v0);
        if (p1) acc8(acc, v1);
    }
    // reduce across stride-2 lanes (rows residues); lanes 0/1 of each group get totals.
#pragma unroll
    for (int off = 2; off <= 8; off <<= 1) {
#pragma unroll
        for (int c = 0; c < 8; c++) acc[c] += __shfl_down(acc[c], off, 64);
    }
    float s = 0.f, q = 0.f;
    if (d < N && r < 2) {
        float dd = dinv[d];
        uint4 hv = ((const uint4*)(hs + (size_t)d * 16))[half];
        float self[8];
        self[0] = bf2f((unsigned short)(hv.x & 0xFFFFu)); self[1] = bf2f((unsigned short)(hv.x >> 16));
        self[2] = bf2f((unsigned short)(hv.y & 0xFFFFu)); self[3] = bf2f((unsigned short)(hv.y >> 16));
        self[4] = bf2f((unsigned short)(hv.z & 0xFFFFu)); self[5] = bf2f((unsigned short)(hv.z >> 16));
        self[6] = bf2f((unsigned short)(hv.w & 0xFFFFu)); self[7] = bf2f((unsigned short)(hv.w >> 16));
        float o[8];
#pragma unroll
        for (int c = 0; c < 8; c++) o[c] = (acc[c] + self[c]) * dd;
        float* an = agg + (size_t)d * 16 + half * 8;
        *(float4*)(an)     = make_float4(o[0], o[1], o[2], o[3]);
        *(float4*)(an + 4) = make_float4(o[4], o[5], o[6], o[7]);
        const float* bp = bias + half * 8;
        float4 b0 = *(const float4*)bp, b1 = *(const float4*)(bp + 4);
        float a0 = o[0] + b0.x, a1 = o[1] + b0.y, a2 = o[2] + b0.z, a3 = o[3] + b0.w;
        float a4 = o[4] + b1.x, a5 = o[5] + b1.y, a6 = o[6] + b1.z, a7 = o[7] + b1.w;
        s = (a0 + a1) + (a2 + a3) + (a4 + a5) + (a6 + a7);
        q = a0 * a0 + a1 * a1 + a2 * a2 + a3 * a3 + a4 * a4 + a5 * a5 + a6 * a6 + a7 * a7;
    }
    for (int off = 32; off > 0; off >>= 1) {
        s += __shfl_down(s, off, 64);
        q += __shfl_down(q, off, 64);
    }
    __shared__ float ss[4], qq[4];
    int lane = t & 63, wid = t >> 6;
    if (lane == 0) { ss[wid] = s; qq[wid] = q; }
    __syncthreads();
    if (t == 0)
        part[blockIdx.x] = make_float2(ss[0] + ss[1] + ss[2] + ss[3],
                                       qq[0] + qq[1] + qq[2] + qq[3]);
}

// single-block reduction of per-block partials -> scal (plain stores, no atomics)
__global__ __launch_bounds__(256) void k_statsred(const float2* __restrict__ part,
                                                  float* __restrict__ scal, int M) {
    int t = threadIdx.x;
    float s = 0.f, q = 0.f;
    for (int i = t; i < M; i += 256) {
        float2 v = part[i];
        s += v.x; q += v.y;
    }
    for (int off = 32; off > 0; off >>= 1) {
        s += __shfl_down(s, off, 64);
        q += __shfl_down(q, off, 64);
    }
    __shared__ float ss[4], qq[4];
    int lane = t & 63, wid = t >> 6;
    if (lane == 0) { ss[wid] = s; qq[wid] = q; }
    __syncthreads();
    if (t == 0) {
        scal[0] = ss[0] + ss[1] + ss[2] + ss[3];
        scal[1] = qq[0] + qq[1] + qq[2] + qq[3];
    }
}

// per batch row: LN + PReLU on 16 channels, then x trans[16,128] -> out[B,128]
__global__ __launch_bounds__(256) void k_final(const float* __restrict__ agg,
                                               const int* __restrict__ batch,
                                               const float* __restrict__ trans,
                                               const float* __restrict__ bias,
                                               const float* __restrict__ ln_w,
                                               const float* __restrict__ ln_b,
                                               const float* __restrict__ prelu_a,
                                               const float* __restrict__ scal,
                                               float* __restrict__ out, int B, float invCnt) {
    __shared__ float tl[16 * 128];
    __shared__ float hh[2 * 16];
    const int tid = threadIdx.x;
    for (int i = tid; i < 2048; i += 256) tl[i] = trans[i];
    float mean = scal[0] * invCnt;
    float var  = scal[1] * invCnt - mean * mean;
    float inv  = rsqrtf(var + EPS);
    int row0 = blockIdx.x * 2;
    if (tid < 32) {
        int lr = tid >> 4, r = tid & 15;
        int row = row0 + lr;
        if (row < B) {
            int node = batch[row];
            float v = agg[(size_t)node * 16 + r] + bias[r];
            v = (v - mean) * inv * ln_w[r] + ln_b[r];
            float a = prelu_a[0];
            v = v >= 0.f ? v : a * v;
            hh[lr * 16 + r] = v;
        }
    }
    __syncthreads();
    int lr = tid >> 7, d = tid & 127;
    int row = row0 + lr;
    if (row >= B) return;
    const float* hrow = hh + lr * 16;
    float acc = 0.f;
#pragma unroll
    for (int r = 0; r < 16; r++) acc += hrow[r] * tl[r * 128 + d];
    out[(size_t)row * 128 + d] = acc;
}

extern "C" void kernel_launch(void* const* d_in, const int* in_sizes, int n_in,
                              void* d_out, int out_size, void* d_ws, size_t ws_size,
                              hipStream_t stream) {
    const float* x       = (const float*)d_in[0];
    const int*   ei      = (const int*)d_in[1];
    const float* trans   = (const float*)d_in[2];
    const int*   batch   = (const int*)d_in[3];
    const float* W       = (const float*)d_in[4];
    const float* bias    = (const float*)d_in[5];
    const float* ln_w    = (const float*)d_in[6];
    const float* ln_b    = (const float*)d_in[7];
    const float* prelu_a = (const float*)d_in[8];
    float* out = (float*)d_out;

    const int N = in_sizes[0] / 256;   // 100000
    const int E = in_sizes[1] / 2;     // 3200000
    const int B = in_sizes[3];         // 16384
    const int NB = (N + BSIZE - 1) >> BSHIFT;   // 391
    const int NBLK = (N + 15) / 16;    // 6250 agg blocks

    char* p = (char*)d_ws;
    unsigned short* hs = (unsigned short*)p;  p += (size_t)N * 16 * 2;    // 3.2MB bf16
    float*    agg     = (float*)p;     p += (size_t)N * 16 * 4;           // 6.4MB
    unsigned* sorted  = (unsigned*)p;  p += (size_t)E * 4;                // 12.8MB
    unsigned* sorted2 = (unsigned*)p;  p += (size_t)E * 4;                // 12.8MB
    float*    dinv    = (float*)p;     p += (size_t)N * 4;
    unsigned* nstart  = (unsigned*)p;  p += (size_t)(N + 1) * 4;
    unsigned* ghist   = (unsigned*)p;  p += NBMAX * 4;
    unsigned* base    = (unsigned*)p;  p += (NBMAX + 1) * 4;
    unsigned* cursor  = (unsigned*)p;  p += NBMAX * 4;
    float*    scal    = (float*)p;     p += 2 * 4;
    p = (char*)(((size_t)p + 7) & ~(size_t)7);
    float2*   part    = (float2*)p;    p += (size_t)NBLK * 8;             // 50KB

    int E4 = E >> 2;
    int pb = (E4 + 1023) / 1024;       // 4096 edges per block

    hipLaunchKernelGGL(k_zero,     dim3(1),               dim3(512), 0, stream, ghist, NB);
    hipLaunchKernelGGL(k_bhist,    dim3(pb),              dim3(256), 0, stream, ei, ghist, E, NB);
    hipLaunchKernelGGL(k_bscan,    dim3(1),               dim3(512), 0, stream, ghist, base, cursor, nstart, NB, N, E);
    hipLaunchKernelGGL(k_bpart,    dim3(pb),              dim3(256), 0, stream, ei, cursor, sorted, E, NB);
    hipLaunchKernelGGL(k_bdeg2,    dim3(NB),              dim3(256), 0, stream, base, sorted, nstart, dinv, N);
    hipLaunchKernelGGL(k_bsort,    dim3(NB),              dim3(256), 0, stream, base, nstart, sorted, sorted2, N);
    hipLaunchKernelGGL(k_gemm,     dim3((N + 255) / 256), dim3(256), 0, stream, x, W, dinv, hs, N);
    hipLaunchKernelGGL(k_agg3,     dim3(NBLK),            dim3(256), 0, stream, nstart, sorted2, hs, dinv, bias, agg, part, N);
    hipLaunchKernelGGL(k_statsred, dim3(1),               dim3(256), 0, stream, part, scal, NBLK);
    hipLaunchKernelGGL(k_final,    dim3((B + 1) / 2),     dim3(256), 0, stream, agg, batch, trans, bias,
                       ln_w, ln_b, prelu_a, scal, out, B, 1.0f / (float)(N * 16));
}